// Round 6
// baseline (372.074 us; speedup 1.0000x reference)
//
#include <hip/hip_runtime.h>

typedef _Float16 f16;
typedef f16 f16x8 __attribute__((ext_vector_type(8)));
typedef float f32x4 __attribute__((ext_vector_type(4)));

#define NN 4096
#define MM 64
#define EE 256
#define CC 128

__device__ __forceinline__ f32x4 mfma16(f16x8 a, f16x8 b, f32x4 c) {
  return __builtin_amdgcn_mfma_f32_16x16x32_f16(a, b, c, 0, 0, 0);
}

// ---------------------------------------------------------------------------
// P0: transpose + fp16 hi/lo split of projection weights.
// W[e][c] f32 -> WTh/WTl[c][e] f16 (h + l reconstructs fp32 to ~2^-22)
// grid: 8 blocks (job = bx>>2 in {Wk,Wv}, e-chunk = bx&3), 256 threads
// ---------------------------------------------------------------------------
__global__ __launch_bounds__(256) void wt_kernel(
    const float* __restrict__ Wk, const float* __restrict__ Wv,
    f16* __restrict__ WkTh, f16* __restrict__ WkTl,
    f16* __restrict__ WvTh, f16* __restrict__ WvTl) {
  __shared__ __align__(16) float wlds[64][132];
  const int job = blockIdx.x >> 2;
  const int e0 = (blockIdx.x & 3) * 64;
  const float* __restrict__ W = job ? Wv : Wk;
  f16* __restrict__ WTh = job ? WvTh : WkTh;
  f16* __restrict__ WTl = job ? WvTl : WkTl;
  const int t = threadIdx.x;
  {
    const int er = t >> 2, c0 = (t & 3) * 32;
#pragma unroll
    for (int i = 0; i < 8; ++i) {
      float4 v = *(const float4*)&W[(e0 + er) * CC + c0 + 4 * i];
      *(float4*)&wlds[er][c0 + 4 * i] = v;
    }
  }
  __syncthreads();
  const int c = t >> 1, eh = (t & 1) * 32;
#pragma unroll
  for (int s = 0; s < 4; ++s) {
    f16x8 hh, ll;
#pragma unroll
    for (int j = 0; j < 8; ++j) {
      float v = wlds[eh + 8 * s + j][c];
      f16 h = (f16)v;
      hh[j] = h;
      ll[j] = (f16)(v - (float)h);
    }
    *(f16x8*)&WTh[c * EE + e0 + eh + 8 * s] = hh;
    *(f16x8*)&WTl[c * EE + e0 + eh + 8 * s] = ll;
  }
}

// ---------------------------------------------------------------------------
// prep: 4 blocks per batch (jb = bx&3):
//   jb 0/1: kln = LN(key[b]); K2[m][c] = kln @ Wk, c-half jb   (linear, h+l)
//   jb 2/3: VT[c][m] = (value[b] @ Wv)^T, c-half jb-2          (linear, h+l)
// All operands hi/lo split -> 3-term MFMA -> fp32-accurate results.
// grid: 256 blocks, 256 threads (4 waves)
// ---------------------------------------------------------------------------
__global__ __launch_bounds__(256) void prep_kernel(
    const float* __restrict__ keyp, const float* __restrict__ valp,
    const float* __restrict__ g1, const float* __restrict__ b1,
    const f16* __restrict__ WkTh, const f16* __restrict__ WkTl,
    const f16* __restrict__ WvTh, const f16* __restrict__ WvTl,
    f16* __restrict__ K2h, f16* __restrict__ K2l,
    f16* __restrict__ VTh, f16* __restrict__ VTl) {
  __shared__ __align__(16) f16 aldsh[64][256];  // 32 KB
  __shared__ __align__(16) f16 aldsl[64][256];  // 32 KB
  const int b = blockIdx.x >> 2, jb = blockIdx.x & 3;
  const int t = threadIdx.x, l = t & 63, w = t >> 6;
  {
    const int m = t >> 2, q0 = (t & 3) * 64;
    const float* __restrict__ src = (jb >= 2 ? valp : keyp) + (b * MM + m) * EE + q0;
    float x[64];
    float s1 = 0.f;
#pragma unroll
    for (int i = 0; i < 16; ++i) {
      float4 v = *(const float4*)&src[4 * i];
      x[4 * i] = v.x; x[4 * i + 1] = v.y; x[4 * i + 2] = v.z; x[4 * i + 3] = v.w;
      s1 += v.x + v.y + v.z + v.w;
    }
    if (jb < 2) {  // LayerNorm over E, two-pass variance (matches reference)
      s1 += __shfl_xor(s1, 1); s1 += __shfl_xor(s1, 2);
      const float mu = s1 * (1.f / EE);
      float s2 = 0.f;
#pragma unroll
      for (int i = 0; i < 64; ++i) { float d = x[i] - mu; s2 += d * d; }
      s2 += __shfl_xor(s2, 1); s2 += __shfl_xor(s2, 2);
      const float rs = 1.f / sqrtf(s2 * (1.f / EE) + 1e-5f);
#pragma unroll
      for (int i = 0; i < 16; ++i) {
        float4 gv = *(const float4*)&g1[q0 + 4 * i];
        float4 bv = *(const float4*)&b1[q0 + 4 * i];
        x[4 * i]     = (x[4 * i]     - mu) * rs * gv.x + bv.x;
        x[4 * i + 1] = (x[4 * i + 1] - mu) * rs * gv.y + bv.y;
        x[4 * i + 2] = (x[4 * i + 2] - mu) * rs * gv.z + bv.z;
        x[4 * i + 3] = (x[4 * i + 3] - mu) * rs * gv.w + bv.w;
      }
    }
#pragma unroll
    for (int s = 0; s < 8; ++s) {
      f16x8 hh, ll;
#pragma unroll
      for (int j = 0; j < 8; ++j) {
        float v = x[8 * s + j];
        f16 h = (f16)v;
        hh[j] = h;
        ll[j] = (f16)(v - (float)h);
      }
      *(f16x8*)&aldsh[m][q0 + 8 * s] = hh;
      *(f16x8*)&aldsl[m][q0 + 8 * s] = ll;
    }
  }
  __syncthreads();
  const int l15 = l & 15, lo = (l >> 4) * 8;
  if (jb < 2) {
    f16x8 ah[8], al[8];
#pragma unroll
    for (int kk = 0; kk < 8; ++kk) {
      ah[kk] = *(const f16x8*)&aldsh[16 * w + l15][32 * kk + lo];
      al[kk] = *(const f16x8*)&aldsl[16 * w + l15][32 * kk + lo];
    }
#pragma unroll
    for (int gg = 0; gg < 4; ++gg) {
      const int g = 4 * jb + gg;
      f32x4 acc = {0.f, 0.f, 0.f, 0.f};
#pragma unroll
      for (int kk = 0; kk < 8; ++kk) {
        f16x8 bh = *(const f16x8*)&WkTh[(16 * g + l15) * EE + 32 * kk + lo];
        f16x8 bl = *(const f16x8*)&WkTl[(16 * g + l15) * EE + 32 * kk + lo];
        acc = mfma16(ah[kk], bh, acc);
        acc = mfma16(al[kk], bh, acc);
        acc = mfma16(ah[kk], bl, acc);
      }
#pragma unroll
      for (int j = 0; j < 4; ++j) {
        const int mrow = 16 * w + 4 * (l >> 4) + j;
        const int ccol = 16 * g + l15;
        const int idx = b * (MM * CC) + mrow * CC + ccol;  // linear
        float v = acc[j];
        f16 h = (f16)v;
        K2h[idx] = h;
        K2l[idx] = (f16)(v - (float)h);
      }
    }
  } else {
    const int ct = 16 * (w + 4 * (jb - 2));
    f16x8 ah[8], al[8];
#pragma unroll
    for (int kk = 0; kk < 8; ++kk) {
      ah[kk] = *(const f16x8*)&WvTh[(ct + l15) * EE + 32 * kk + lo];
      al[kk] = *(const f16x8*)&WvTl[(ct + l15) * EE + 32 * kk + lo];
    }
#pragma unroll
    for (int g = 0; g < 4; ++g) {
      f32x4 acc = {0.f, 0.f, 0.f, 0.f};
#pragma unroll
      for (int kk = 0; kk < 8; ++kk) {
        f16x8 bh = *(const f16x8*)&aldsh[16 * g + l15][32 * kk + lo];
        f16x8 bl = *(const f16x8*)&aldsl[16 * g + l15][32 * kk + lo];
        acc = mfma16(ah[kk], bh, acc);
        acc = mfma16(al[kk], bh, acc);
        acc = mfma16(ah[kk], bl, acc);
      }
#pragma unroll
      for (int j = 0; j < 4; ++j) {
        const int crow = ct + 4 * (l >> 4) + j;
        const int mcol = 16 * g + l15;
        const int idx = b * (CC * MM) + crow * MM + mcol;  // linear
        float v = acc[j];
        f16 h = (f16)v;
        VTh[idx] = h;
        VTl[idx] = (f16)(v - (float)h);
      }
    }
  }
}

// ---------------------------------------------------------------------------
// main: fused LN(q) + QK^T + softmax(M=64) + PV, all hi/lo-split (fp32-acc).
// No K2/VT LDS staging: B-fragments read directly from global (L2-hot via
// XCD-bijective swizzle; fragment pattern is 64B-line coalesced). LDS only
// holds the per-wave P transpose (16 KB total). Zero __syncthreads.
// 64 q-rows/block, 4 waves. grid: 4096 blocks.
// ---------------------------------------------------------------------------
__global__ __launch_bounds__(256, 5) void attn_kernel(
    const float* __restrict__ qin,
    const f16* __restrict__ K2hg, const f16* __restrict__ K2lg,
    const f16* __restrict__ VThg, const f16* __restrict__ VTlg,
    const float* __restrict__ g2, const float* __restrict__ b2,
    float* __restrict__ outp) {
  __shared__ __align__(16) f16 pldsh[4][1024];  // 8 KB, per-wave P-hi
  __shared__ __align__(16) f16 pldsl[4][1024];  // 8 KB, per-wave P-lo
  const int bid = blockIdx.x;
  const int swz = (bid & 7) * 512 + (bid >> 3);  // 4096%8==0: bijective
  const int b = swz >> 6, tile = swz & 63;
  const int t = threadIdx.x, l = t & 63, w = t >> 6;
  const int l15 = l & 15, lo = (l >> 4) * 8, swl = 8 * (l & 7);

  const f16* __restrict__ k2hb = K2hg + b * (MM * CC);
  const f16* __restrict__ k2lb = K2lg + b * (MM * CC);
  const f16* __restrict__ vthb = VThg + b * (CC * MM);
  const f16* __restrict__ vtlb = VTlg + b * (CC * MM);

  // load Q in A-fragment layout: lane -> row l15, c-chunks by l>>4
  const int r = tile * 64 + 16 * w + l15;
  const float* __restrict__ qrow = qin + (b * NN + r) * CC;
  float x[4][8];
  float s1 = 0.f;
#pragma unroll
  for (int kk = 0; kk < 4; ++kk) {
    float4 v0 = *(const float4*)&qrow[32 * kk + lo];
    float4 v1 = *(const float4*)&qrow[32 * kk + lo + 4];
    x[kk][0] = v0.x; x[kk][1] = v0.y; x[kk][2] = v0.z; x[kk][3] = v0.w;
    x[kk][4] = v1.x; x[kk][5] = v1.y; x[kk][6] = v1.z; x[kk][7] = v1.w;
    s1 += v0.x + v0.y + v0.z + v0.w + v1.x + v1.y + v1.z + v1.w;
  }
  // row stats across lanes {l15, l15+16, l15+32, l15+48}
  s1 += __shfl_xor(s1, 16); s1 += __shfl_xor(s1, 32);
  const float mu = s1 * (1.f / CC);
  float s2 = 0.f;
#pragma unroll
  for (int kk = 0; kk < 4; ++kk)
#pragma unroll
    for (int j = 0; j < 8; ++j) { float d = x[kk][j] - mu; s2 += d * d; }
  s2 += __shfl_xor(s2, 16); s2 += __shfl_xor(s2, 32);
  const float rs = 1.f / sqrtf(s2 * (1.f / CC) + 1e-5f);

  // LN in fp32 + hi/lo split of q
  f16x8 aqh[4], aql[4];
#pragma unroll
  for (int kk = 0; kk < 4; ++kk) {
    float4 g0 = *(const float4*)&g2[32 * kk + lo];
    float4 g1v = *(const float4*)&g2[32 * kk + lo + 4];
    float4 c0 = *(const float4*)&b2[32 * kk + lo];
    float4 c1 = *(const float4*)&b2[32 * kk + lo + 4];
    float gg[8] = {g0.x, g0.y, g0.z, g0.w, g1v.x, g1v.y, g1v.z, g1v.w};
    float bb[8] = {c0.x, c0.y, c0.z, c0.w, c1.x, c1.y, c1.z, c1.w};
#pragma unroll
    for (int j = 0; j < 8; ++j) {
      float y = (x[kk][j] - mu) * rs * gg[j] + bb[j];
      f16 h = (f16)y;
      aqh[kk][j] = h;
      aql[kk][j] = (f16)(y - (float)h);
    }
  }

  // S = Q @ K2^T : 4 m-tiles x 4 k-steps x 3 hi/lo terms, B-frags from L2
  f32x4 sa[4];
#pragma unroll
  for (int g = 0; g < 4; ++g) sa[g] = (f32x4){0.f, 0.f, 0.f, 0.f};
#pragma unroll
  for (int g = 0; g < 4; ++g)
#pragma unroll
    for (int kk = 0; kk < 4; ++kk) {
      const int co = (16 * g + l15) * CC + 32 * kk + lo;
      f16x8 bh = *(const f16x8*)&k2hb[co];
      f16x8 bl = *(const f16x8*)&k2lb[co];
      sa[g] = mfma16(aqh[kk], bh, sa[g]);
      sa[g] = mfma16(aql[kk], bh, sa[g]);
      sa[g] = mfma16(aqh[kk], bl, sa[g]);
    }

  // softmax over m (cols = 16g + l15; rows j within lane group l&15)
  float mx[4], rinv[4];
#pragma unroll
  for (int j = 0; j < 4; ++j) {
    float v = fmaxf(fmaxf(sa[0][j], sa[1][j]), fmaxf(sa[2][j], sa[3][j]));
    v = fmaxf(v, __shfl_xor(v, 1));
    v = fmaxf(v, __shfl_xor(v, 2));
    v = fmaxf(v, __shfl_xor(v, 4));
    v = fmaxf(v, __shfl_xor(v, 8));
    mx[j] = v;
  }
#pragma unroll
  for (int g = 0; g < 4; ++g)
#pragma unroll
    for (int j = 0; j < 4; ++j) sa[g][j] = expf(sa[g][j] - mx[j]);
#pragma unroll
  for (int j = 0; j < 4; ++j) {
    float v = sa[0][j] + sa[1][j] + sa[2][j] + sa[3][j];
    v += __shfl_xor(v, 1);
    v += __shfl_xor(v, 2);
    v += __shfl_xor(v, 4);
    v += __shfl_xor(v, 8);
    rinv[j] = 1.f / v;
  }

  // P (hi/lo) -> per-wave LDS transpose (D-layout -> A-layout), swizzled
#pragma unroll
  for (int g = 0; g < 4; ++g)
#pragma unroll
    for (int j = 0; j < 4; ++j) {
      const int rl = 4 * (l >> 4) + j;
      const int mc = 16 * g + l15;
      const int pi = rl * 64 + (mc ^ (8 * (rl & 7)));
      const float p = sa[g][j] * rinv[j];
      const f16 ph = (f16)p;
      pldsh[w][pi] = ph;
      pldsl[w][pi] = (f16)(p - (float)ph);
    }
  asm volatile("s_waitcnt lgkmcnt(0)" ::: "memory");
  __builtin_amdgcn_sched_barrier(0);

  // O = P @ V : 8 c-tiles x 2 k-steps x 3 hi/lo terms, V-frags from L2
  f16x8 aph[2], apl[2];
#pragma unroll
  for (int ks = 0; ks < 2; ++ks) {
    const int po = l15 * 64 + ((32 * ks + lo) ^ swl);
    aph[ks] = *(const f16x8*)&pldsh[w][po];
    apl[ks] = *(const f16x8*)&pldsl[w][po];
  }
  f32x4 oa[8];
#pragma unroll
  for (int g = 0; g < 8; ++g) oa[g] = (f32x4){0.f, 0.f, 0.f, 0.f};
#pragma unroll
  for (int g = 0; g < 8; ++g)
#pragma unroll
    for (int ks = 0; ks < 2; ++ks) {
      const int vo = (16 * g + l15) * MM + 32 * ks + lo;
      f16x8 bh = *(const f16x8*)&vthb[vo];
      f16x8 bl = *(const f16x8*)&vtlb[vo];
      oa[g] = mfma16(aph[ks], bh, oa[g]);
      oa[g] = mfma16(apl[ks], bh, oa[g]);
      oa[g] = mfma16(aph[ks], bl, oa[g]);
    }

  // store fp32 output
  const int rb = (b * NN + tile * 64 + 16 * w + 4 * (l >> 4)) * CC;
#pragma unroll
  for (int g = 0; g < 8; ++g)
#pragma unroll
    for (int j = 0; j < 4; ++j)
      outp[rb + j * CC + 16 * g + l15] = oa[g][j];
}

// ---------------------------------------------------------------------------
extern "C" void kernel_launch(void* const* d_in, const int* in_sizes, int n_in,
                              void* d_out, int out_size, void* d_ws, size_t ws_size,
                              hipStream_t stream) {
  (void)in_sizes; (void)n_in; (void)out_size; (void)ws_size;
  const float* q   = (const float*)d_in[0];
  const float* key = (const float*)d_in[1];
  const float* val = (const float*)d_in[2];
  const float* wk  = (const float*)d_in[3];
  const float* wv  = (const float*)d_in[4];
  const float* g1  = (const float*)d_in[5];
  const float* b1  = (const float*)d_in[6];
  const float* g2  = (const float*)d_in[7];
  const float* b2  = (const float*)d_in[8];
  float* out = (float*)d_out;

  char* ws = (char*)d_ws;
  f16* WkTh = (f16*)(ws);                           // 64 KB each
  f16* WkTl = (f16*)(ws + 65536);
  f16* WvTh = (f16*)(ws + 131072);
  f16* WvTl = (f16*)(ws + 196608);
  f16* K2h  = (f16*)(ws + 262144);                  // 1 MB each
  f16* K2l  = (f16*)(ws + 262144 + 1048576);
  f16* VTh  = (f16*)(ws + 262144 + 2097152);
  f16* VTl  = (f16*)(ws + 262144 + 3145728);

  wt_kernel<<<8, 256, 0, stream>>>(wk, wv, WkTh, WkTl, WvTh, WvTl);
  prep_kernel<<<256, 256, 0, stream>>>(key, val, g1, b1, WkTh, WkTl, WvTh, WvTl,
                                       K2h, K2l, VTh, VTl);
  attn_kernel<<<4096, 256, 0, stream>>>(q, K2h, K2l, VTh, VTl, g2, b2, out);
}

// Round 7
// 277.842 us; speedup vs baseline: 1.3392x; 1.3392x over previous
//
#include <hip/hip_runtime.h>

typedef _Float16 f16;
typedef f16 f16x8 __attribute__((ext_vector_type(8)));
typedef float f32x4 __attribute__((ext_vector_type(4)));

#define NN 4096
#define MM 64
#define EE 256
#define CC 128

__device__ __forceinline__ f32x4 mfma16(f16x8 a, f16x8 b, f32x4 c) {
  return __builtin_amdgcn_mfma_f32_16x16x32_f16(a, b, c, 0, 0, 0);
}

// ---------------------------------------------------------------------------
// P0: transpose + fp16 hi/lo split of projection weights.
// W[e][c] f32 -> WTh/WTl[c][e] f16 (h + l reconstructs fp32 to ~2^-22)
// grid: 8 blocks (job = bx>>2 in {Wk,Wv}, e-chunk = bx&3), 256 threads
// ---------------------------------------------------------------------------
__global__ __launch_bounds__(256) void wt_kernel(
    const float* __restrict__ Wk, const float* __restrict__ Wv,
    f16* __restrict__ WkTh, f16* __restrict__ WkTl,
    f16* __restrict__ WvTh, f16* __restrict__ WvTl) {
  __shared__ __align__(16) float wlds[64][132];
  const int job = blockIdx.x >> 2;
  const int e0 = (blockIdx.x & 3) * 64;
  const float* __restrict__ W = job ? Wv : Wk;
  f16* __restrict__ WTh = job ? WvTh : WkTh;
  f16* __restrict__ WTl = job ? WvTl : WkTl;
  const int t = threadIdx.x;
  {
    const int er = t >> 2, c0 = (t & 3) * 32;
#pragma unroll
    for (int i = 0; i < 8; ++i) {
      float4 v = *(const float4*)&W[(e0 + er) * CC + c0 + 4 * i];
      *(float4*)&wlds[er][c0 + 4 * i] = v;
    }
  }
  __syncthreads();
  const int c = t >> 1, eh = (t & 1) * 32;
#pragma unroll
  for (int s = 0; s < 4; ++s) {
    f16x8 hh, ll;
#pragma unroll
    for (int j = 0; j < 8; ++j) {
      float v = wlds[eh + 8 * s + j][c];
      f16 h = (f16)v;
      hh[j] = h;
      ll[j] = (f16)(v - (float)h);
    }
    *(f16x8*)&WTh[c * EE + e0 + eh + 8 * s] = hh;
    *(f16x8*)&WTl[c * EE + e0 + eh + 8 * s] = ll;
  }
}

// ---------------------------------------------------------------------------
// prep: 4 blocks per batch (jb = bx&3):
//   jb 0/1: kln = LN(key[b]); K2[m][c] = kln @ Wk, c-half jb   (swizzled, h+l)
//   jb 2/3: VT[c][m] = (value[b] @ Wv)^T, c-half jb-2          (swizzled, h ONLY)
// Compute is 3-term hi/lo MFMA (fp32-accurate); storage precision differs:
// K2 stored h+l (feeds the S-path), VT stored single f16 (PV-path, error
// budget ~1e-4 in output vs threshold 3e-2).
// grid: 256 blocks, 256 threads (4 waves)
// ---------------------------------------------------------------------------
__global__ __launch_bounds__(256) void prep_kernel(
    const float* __restrict__ keyp, const float* __restrict__ valp,
    const float* __restrict__ g1, const float* __restrict__ b1,
    const f16* __restrict__ WkTh, const f16* __restrict__ WkTl,
    const f16* __restrict__ WvTh, const f16* __restrict__ WvTl,
    f16* __restrict__ K2h, f16* __restrict__ K2l,
    f16* __restrict__ VTh) {
  __shared__ __align__(16) f16 aldsh[64][256];  // 32 KB
  __shared__ __align__(16) f16 aldsl[64][256];  // 32 KB
  const int b = blockIdx.x >> 2, jb = blockIdx.x & 3;
  const int t = threadIdx.x, l = t & 63, w = t >> 6;
  {
    const int m = t >> 2, q0 = (t & 3) * 64;
    const float* __restrict__ src = (jb >= 2 ? valp : keyp) + (b * MM + m) * EE + q0;
    float x[64];
    float s1 = 0.f;
#pragma unroll
    for (int i = 0; i < 16; ++i) {
      float4 v = *(const float4*)&src[4 * i];
      x[4 * i] = v.x; x[4 * i + 1] = v.y; x[4 * i + 2] = v.z; x[4 * i + 3] = v.w;
      s1 += v.x + v.y + v.z + v.w;
    }
    if (jb < 2) {  // LayerNorm over E, two-pass variance (matches reference)
      s1 += __shfl_xor(s1, 1); s1 += __shfl_xor(s1, 2);
      const float mu = s1 * (1.f / EE);
      float s2 = 0.f;
#pragma unroll
      for (int i = 0; i < 64; ++i) { float d = x[i] - mu; s2 += d * d; }
      s2 += __shfl_xor(s2, 1); s2 += __shfl_xor(s2, 2);
      const float rs = 1.f / sqrtf(s2 * (1.f / EE) + 1e-5f);
#pragma unroll
      for (int i = 0; i < 16; ++i) {
        float4 gv = *(const float4*)&g1[q0 + 4 * i];
        float4 bv = *(const float4*)&b1[q0 + 4 * i];
        x[4 * i]     = (x[4 * i]     - mu) * rs * gv.x + bv.x;
        x[4 * i + 1] = (x[4 * i + 1] - mu) * rs * gv.y + bv.y;
        x[4 * i + 2] = (x[4 * i + 2] - mu) * rs * gv.z + bv.z;
        x[4 * i + 3] = (x[4 * i + 3] - mu) * rs * gv.w + bv.w;
      }
    }
#pragma unroll
    for (int s = 0; s < 8; ++s) {
      f16x8 hh, ll;
#pragma unroll
      for (int j = 0; j < 8; ++j) {
        float v = x[8 * s + j];
        f16 h = (f16)v;
        hh[j] = h;
        ll[j] = (f16)(v - (float)h);
      }
      *(f16x8*)&aldsh[m][q0 + 8 * s] = hh;
      *(f16x8*)&aldsl[m][q0 + 8 * s] = ll;
    }
  }
  __syncthreads();
  const int l15 = l & 15, lo = (l >> 4) * 8;
  if (jb < 2) {
    f16x8 ah[8], al[8];
#pragma unroll
    for (int kk = 0; kk < 8; ++kk) {
      ah[kk] = *(const f16x8*)&aldsh[16 * w + l15][32 * kk + lo];
      al[kk] = *(const f16x8*)&aldsl[16 * w + l15][32 * kk + lo];
    }
#pragma unroll
    for (int gg = 0; gg < 4; ++gg) {
      const int g = 4 * jb + gg;
      f32x4 acc = {0.f, 0.f, 0.f, 0.f};
#pragma unroll
      for (int kk = 0; kk < 8; ++kk) {
        f16x8 bh = *(const f16x8*)&WkTh[(16 * g + l15) * EE + 32 * kk + lo];
        f16x8 bl = *(const f16x8*)&WkTl[(16 * g + l15) * EE + 32 * kk + lo];
        acc = mfma16(ah[kk], bh, acc);
        acc = mfma16(al[kk], bh, acc);
        acc = mfma16(ah[kk], bl, acc);
      }
#pragma unroll
      for (int j = 0; j < 4; ++j) {
        const int mrow = 16 * w + 4 * (l >> 4) + j;
        const int ccol = 16 * g + l15;
        const int idx = b * (MM * CC) + mrow * CC + (ccol ^ (8 * (mrow & 7)));
        float v = acc[j];
        f16 h = (f16)v;
        K2h[idx] = h;
        K2l[idx] = (f16)(v - (float)h);
      }
    }
  } else {
    const int ct = 16 * (w + 4 * (jb - 2));
    f16x8 ah[8], al[8];
#pragma unroll
    for (int kk = 0; kk < 8; ++kk) {
      ah[kk] = *(const f16x8*)&WvTh[(ct + l15) * EE + 32 * kk + lo];
      al[kk] = *(const f16x8*)&WvTl[(ct + l15) * EE + 32 * kk + lo];
    }
#pragma unroll
    for (int g = 0; g < 4; ++g) {
      f32x4 acc = {0.f, 0.f, 0.f, 0.f};
#pragma unroll
      for (int kk = 0; kk < 8; ++kk) {
        f16x8 bh = *(const f16x8*)&aldsh[16 * g + l15][32 * kk + lo];
        f16x8 bl = *(const f16x8*)&aldsl[16 * g + l15][32 * kk + lo];
        acc = mfma16(ah[kk], bh, acc);
        acc = mfma16(al[kk], bh, acc);
        acc = mfma16(ah[kk], bl, acc);
      }
#pragma unroll
      for (int j = 0; j < 4; ++j) {
        const int crow = ct + 4 * (l >> 4) + j;
        const int mcol = 16 * g + l15;
        const int idx = b * (CC * MM) + crow * MM + (mcol ^ (8 * (crow & 7)));
        VTh[idx] = (f16)acc[j];
      }
    }
  }
}

// ---------------------------------------------------------------------------
// main: fused LN(q) + QK^T + softmax(M=64) + PV.
// LDS staging restored (round-6 L2-direct was 2x slower: latency-bound at
// 44 VGPRs, MfmaUtil 5.6%). Footprint cut 64->48 KB (VT h-only, P single
// f16 reusing k2h space) -> 3 blocks/CU. S-path stays full hi/lo 3-term.
// 64 q-rows/block, 4 waves. grid: 4096 blocks (XCD-bijective swizzle).
// ---------------------------------------------------------------------------
__global__ __launch_bounds__(256, 3) void attn_kernel(
    const float* __restrict__ qin,
    const f16* __restrict__ K2hg, const f16* __restrict__ K2lg,
    const f16* __restrict__ VThg,
    const float* __restrict__ g2, const float* __restrict__ b2,
    float* __restrict__ outp) {
  __shared__ __align__(16) f16 k2h[MM * CC];  // 16 KB, swizzled; P reuses after S
  __shared__ __align__(16) f16 k2l[MM * CC];  // 16 KB
  __shared__ __align__(16) f16 vth[CC * MM];  // 16 KB, swizzled
  const int bid = blockIdx.x;
  const int swz = (bid & 7) * 512 + (bid >> 3);  // 4096%8==0: bijective
  const int b = swz >> 6, tile = swz & 63;
  const int t = threadIdx.x, l = t & 63, w = t >> 6;
  const int l15 = l & 15, lo = (l >> 4) * 8, swl = 8 * (l & 7);

  {  // stage K2 h/l + VT h: global layouts pre-swizzled -> linear copy
    const float4* __restrict__ skh = (const float4*)(K2hg + b * (MM * CC));
    const float4* __restrict__ skl = (const float4*)(K2lg + b * (MM * CC));
    const float4* __restrict__ svh = (const float4*)(VThg + b * (CC * MM));
#pragma unroll
    for (int i = 0; i < 4; ++i) {
      const int idx = t + 256 * i;
      ((float4*)k2h)[idx] = skh[idx];
      ((float4*)k2l)[idx] = skl[idx];
      ((float4*)vth)[idx] = svh[idx];
    }
  }

  // load Q in A-fragment layout: lane -> row l15, c-chunks by l>>4
  const int r = tile * 64 + 16 * w + l15;
  const float* __restrict__ qrow = qin + (b * NN + r) * CC;
  float x[4][8];
  float s1 = 0.f;
#pragma unroll
  for (int kk = 0; kk < 4; ++kk) {
    float4 v0 = *(const float4*)&qrow[32 * kk + lo];
    float4 v1 = *(const float4*)&qrow[32 * kk + lo + 4];
    x[kk][0] = v0.x; x[kk][1] = v0.y; x[kk][2] = v0.z; x[kk][3] = v0.w;
    x[kk][4] = v1.x; x[kk][5] = v1.y; x[kk][6] = v1.z; x[kk][7] = v1.w;
    s1 += v0.x + v0.y + v0.z + v0.w + v1.x + v1.y + v1.z + v1.w;
  }
  // row stats across lanes {l15, l15+16, l15+32, l15+48}
  s1 += __shfl_xor(s1, 16); s1 += __shfl_xor(s1, 32);
  const float mu = s1 * (1.f / CC);
  float s2 = 0.f;
#pragma unroll
  for (int kk = 0; kk < 4; ++kk)
#pragma unroll
    for (int j = 0; j < 8; ++j) { float d = x[kk][j] - mu; s2 += d * d; }
  s2 += __shfl_xor(s2, 16); s2 += __shfl_xor(s2, 32);
  const float rs = 1.f / sqrtf(s2 * (1.f / CC) + 1e-5f);

  // LN in fp32 + hi/lo split of q
  f16x8 aqh[4], aql[4];
#pragma unroll
  for (int kk = 0; kk < 4; ++kk) {
    float4 g0 = *(const float4*)&g2[32 * kk + lo];
    float4 g1v = *(const float4*)&g2[32 * kk + lo + 4];
    float4 c0 = *(const float4*)&b2[32 * kk + lo];
    float4 c1 = *(const float4*)&b2[32 * kk + lo + 4];
    float gg[8] = {g0.x, g0.y, g0.z, g0.w, g1v.x, g1v.y, g1v.z, g1v.w};
    float bb[8] = {c0.x, c0.y, c0.z, c0.w, c1.x, c1.y, c1.z, c1.w};
#pragma unroll
    for (int j = 0; j < 8; ++j) {
      float y = (x[kk][j] - mu) * rs * gg[j] + bb[j];
      f16 h = (f16)y;
      aqh[kk][j] = h;
      aql[kk][j] = (f16)(y - (float)h);
    }
  }
  __syncthreads();  // barrier 1: K2/VT staged

  // S = Q @ K2^T : 4 m-tiles x 4 k-steps x 3 hi/lo terms (LDS, swizzled)
  f32x4 sa[4];
#pragma unroll
  for (int g = 0; g < 4; ++g) sa[g] = (f32x4){0.f, 0.f, 0.f, 0.f};
#pragma unroll
  for (int g = 0; g < 4; ++g)
#pragma unroll
    for (int kk = 0; kk < 4; ++kk) {
      const int co = (16 * g + l15) * CC + ((32 * kk + lo) ^ swl);
      f16x8 bh = *(const f16x8*)&k2h[co];
      f16x8 bl = *(const f16x8*)&k2l[co];
      sa[g] = mfma16(aqh[kk], bh, sa[g]);
      sa[g] = mfma16(aql[kk], bh, sa[g]);
      sa[g] = mfma16(aqh[kk], bl, sa[g]);
    }

  // softmax over m (register-only; cols = 16g + l15, rows j in group l&15)
  float mx[4], rinv[4];
#pragma unroll
  for (int j = 0; j < 4; ++j) {
    float v = fmaxf(fmaxf(sa[0][j], sa[1][j]), fmaxf(sa[2][j], sa[3][j]));
    v = fmaxf(v, __shfl_xor(v, 1));
    v = fmaxf(v, __shfl_xor(v, 2));
    v = fmaxf(v, __shfl_xor(v, 4));
    v = fmaxf(v, __shfl_xor(v, 8));
    mx[j] = v;
  }
#pragma unroll
  for (int g = 0; g < 4; ++g)
#pragma unroll
    for (int j = 0; j < 4; ++j) sa[g][j] = expf(sa[g][j] - mx[j]);
#pragma unroll
  for (int j = 0; j < 4; ++j) {
    float v = sa[0][j] + sa[1][j] + sa[2][j] + sa[3][j];
    v += __shfl_xor(v, 1);
    v += __shfl_xor(v, 2);
    v += __shfl_xor(v, 4);
    v += __shfl_xor(v, 8);
    rinv[j] = 1.f / v;
  }

  __syncthreads();  // barrier 2: all waves done reading k2h/k2l -> reuse for P

  // P (single f16) -> per-wave LDS transpose (reused k2h space), swizzled
  f16* __restrict__ plds = &k2h[w * 1024];
#pragma unroll
  for (int g = 0; g < 4; ++g)
#pragma unroll
    for (int j = 0; j < 4; ++j) {
      const int rl = 4 * (l >> 4) + j;
      const int mc = 16 * g + l15;
      plds[rl * 64 + (mc ^ (8 * (rl & 7)))] = (f16)(sa[g][j] * rinv[j]);
    }
  asm volatile("s_waitcnt lgkmcnt(0)" ::: "memory");
  __builtin_amdgcn_sched_barrier(0);

  // O = P @ V : 8 c-tiles x 2 k-steps, single term (V h-only)
  f16x8 ap[2];
#pragma unroll
  for (int ks = 0; ks < 2; ++ks)
    ap[ks] = *(const f16x8*)&plds[l15 * 64 + ((32 * ks + lo) ^ swl)];
  f32x4 oa[8];
#pragma unroll
  for (int g = 0; g < 8; ++g) oa[g] = (f32x4){0.f, 0.f, 0.f, 0.f};
#pragma unroll
  for (int g = 0; g < 8; ++g)
#pragma unroll
    for (int ks = 0; ks < 2; ++ks) {
      f16x8 bv = *(const f16x8*)&vth[(16 * g + l15) * MM + ((32 * ks + lo) ^ swl)];
      oa[g] = mfma16(ap[ks], bv, oa[g]);
    }

  // store fp32 output
  const int rb = (b * NN + tile * 64 + 16 * w + 4 * (l >> 4)) * CC;
#pragma unroll
  for (int g = 0; g < 8; ++g)
#pragma unroll
    for (int j = 0; j < 4; ++j)
      outp[rb + j * CC + 16 * g + l15] = oa[g][j];
}

// ---------------------------------------------------------------------------
extern "C" void kernel_launch(void* const* d_in, const int* in_sizes, int n_in,
                              void* d_out, int out_size, void* d_ws, size_t ws_size,
                              hipStream_t stream) {
  (void)in_sizes; (void)n_in; (void)out_size; (void)ws_size;
  const float* q   = (const float*)d_in[0];
  const float* key = (const float*)d_in[1];
  const float* val = (const float*)d_in[2];
  const float* wk  = (const float*)d_in[3];
  const float* wv  = (const float*)d_in[4];
  const float* g1  = (const float*)d_in[5];
  const float* b1  = (const float*)d_in[6];
  const float* g2  = (const float*)d_in[7];
  const float* b2  = (const float*)d_in[8];
  float* out = (float*)d_out;

  char* ws = (char*)d_ws;
  f16* WkTh = (f16*)(ws);                           // 64 KB each
  f16* WkTl = (f16*)(ws + 65536);
  f16* WvTh = (f16*)(ws + 131072);
  f16* WvTl = (f16*)(ws + 196608);
  f16* K2h  = (f16*)(ws + 262144);                  // 1 MB each
  f16* K2l  = (f16*)(ws + 262144 + 1048576);
  f16* VTh  = (f16*)(ws + 262144 + 2097152);

  wt_kernel<<<8, 256, 0, stream>>>(wk, wv, WkTh, WkTl, WvTh, WvTl);
  prep_kernel<<<256, 256, 0, stream>>>(key, val, g1, b1, WkTh, WkTl, WvTh, WvTl,
                                       K2h, K2l, VTh);
  attn_kernel<<<4096, 256, 0, stream>>>(q, K2h, K2l, VTh, g2, b2, out);
}

// Round 8
// 276.991 us; speedup vs baseline: 1.3433x; 1.0031x over previous
//
#include <hip/hip_runtime.h>

typedef _Float16 f16;
typedef f16 f16x8 __attribute__((ext_vector_type(8)));
typedef float f32x4 __attribute__((ext_vector_type(4)));

#define NN 4096
#define MM 64
#define EE 256
#define CC 128

__device__ __forceinline__ f32x4 mfma16(f16x8 a, f16x8 b, f32x4 c) {
  return __builtin_amdgcn_mfma_f32_16x16x32_f16(a, b, c, 0, 0, 0);
}

// ---------------------------------------------------------------------------
// P0: transpose + fp16 hi/lo split of projection weights.
// W[e][c] f32 -> WTh/WTl[c][e] f16 (h + l reconstructs fp32 to ~2^-22)
// grid: 8 blocks (job = bx>>2 in {Wk,Wv}, e-chunk = bx&3), 256 threads
// ---------------------------------------------------------------------------
__global__ __launch_bounds__(256) void wt_kernel(
    const float* __restrict__ Wk, const float* __restrict__ Wv,
    f16* __restrict__ WkTh, f16* __restrict__ WkTl,
    f16* __restrict__ WvTh, f16* __restrict__ WvTl) {
  __shared__ __align__(16) float wlds[64][132];
  const int job = blockIdx.x >> 2;
  const int e0 = (blockIdx.x & 3) * 64;
  const float* __restrict__ W = job ? Wv : Wk;
  f16* __restrict__ WTh = job ? WvTh : WkTh;
  f16* __restrict__ WTl = job ? WvTl : WkTl;
  const int t = threadIdx.x;
  {
    const int er = t >> 2, c0 = (t & 3) * 32;
#pragma unroll
    for (int i = 0; i < 8; ++i) {
      float4 v = *(const float4*)&W[(e0 + er) * CC + c0 + 4 * i];
      *(float4*)&wlds[er][c0 + 4 * i] = v;
    }
  }
  __syncthreads();
  const int c = t >> 1, eh = (t & 1) * 32;
#pragma unroll
  for (int s = 0; s < 4; ++s) {
    f16x8 hh, ll;
#pragma unroll
    for (int j = 0; j < 8; ++j) {
      float v = wlds[eh + 8 * s + j][c];
      f16 h = (f16)v;
      hh[j] = h;
      ll[j] = (f16)(v - (float)h);
    }
    *(f16x8*)&WTh[c * EE + e0 + eh + 8 * s] = hh;
    *(f16x8*)&WTl[c * EE + e0 + eh + 8 * s] = ll;
  }
}

// ---------------------------------------------------------------------------
// prep: 4 blocks per batch (jb = bx&3):
//   jb 0/1: kln = LN(key[b]); K2[m][c] = kln @ Wk, c-half jb   (swizzled, h+l)
//   jb 2/3: VT[c][m] = (value[b] @ Wv)^T, c-half jb-2          (swizzled, h ONLY)
// Compute is 3-term hi/lo MFMA (fp32-accurate); K2 stored h+l (S-path),
// VT stored single f16 (PV-path; output error ~1e-4 vs threshold 3e-2).
// grid: 256 blocks, 256 threads (4 waves)
// ---------------------------------------------------------------------------
__global__ __launch_bounds__(256) void prep_kernel(
    const float* __restrict__ keyp, const float* __restrict__ valp,
    const float* __restrict__ g1, const float* __restrict__ b1,
    const f16* __restrict__ WkTh, const f16* __restrict__ WkTl,
    const f16* __restrict__ WvTh, const f16* __restrict__ WvTl,
    f16* __restrict__ K2h, f16* __restrict__ K2l,
    f16* __restrict__ VTh) {
  __shared__ __align__(16) f16 aldsh[64][256];  // 32 KB
  __shared__ __align__(16) f16 aldsl[64][256];  // 32 KB
  const int b = blockIdx.x >> 2, jb = blockIdx.x & 3;
  const int t = threadIdx.x, l = t & 63, w = t >> 6;
  {
    const int m = t >> 2, q0 = (t & 3) * 64;
    const float* __restrict__ src = (jb >= 2 ? valp : keyp) + (b * MM + m) * EE + q0;
    float x[64];
    float s1 = 0.f;
#pragma unroll
    for (int i = 0; i < 16; ++i) {
      float4 v = *(const float4*)&src[4 * i];
      x[4 * i] = v.x; x[4 * i + 1] = v.y; x[4 * i + 2] = v.z; x[4 * i + 3] = v.w;
      s1 += v.x + v.y + v.z + v.w;
    }
    if (jb < 2) {  // LayerNorm over E, two-pass variance (matches reference)
      s1 += __shfl_xor(s1, 1); s1 += __shfl_xor(s1, 2);
      const float mu = s1 * (1.f / EE);
      float s2 = 0.f;
#pragma unroll
      for (int i = 0; i < 64; ++i) { float d = x[i] - mu; s2 += d * d; }
      s2 += __shfl_xor(s2, 1); s2 += __shfl_xor(s2, 2);
      const float rs = 1.f / sqrtf(s2 * (1.f / EE) + 1e-5f);
#pragma unroll
      for (int i = 0; i < 16; ++i) {
        float4 gv = *(const float4*)&g1[q0 + 4 * i];
        float4 bv = *(const float4*)&b1[q0 + 4 * i];
        x[4 * i]     = (x[4 * i]     - mu) * rs * gv.x + bv.x;
        x[4 * i + 1] = (x[4 * i + 1] - mu) * rs * gv.y + bv.y;
        x[4 * i + 2] = (x[4 * i + 2] - mu) * rs * gv.z + bv.z;
        x[4 * i + 3] = (x[4 * i + 3] - mu) * rs * gv.w + bv.w;
      }
    }
#pragma unroll
    for (int s = 0; s < 8; ++s) {
      f16x8 hh, ll;
#pragma unroll
      for (int j = 0; j < 8; ++j) {
        float v = x[8 * s + j];
        f16 h = (f16)v;
        hh[j] = h;
        ll[j] = (f16)(v - (float)h);
      }
      *(f16x8*)&aldsh[m][q0 + 8 * s] = hh;
      *(f16x8*)&aldsl[m][q0 + 8 * s] = ll;
    }
  }
  __syncthreads();
  const int l15 = l & 15, lo = (l >> 4) * 8;
  if (jb < 2) {
    f16x8 ah[8], al[8];
#pragma unroll
    for (int kk = 0; kk < 8; ++kk) {
      ah[kk] = *(const f16x8*)&aldsh[16 * w + l15][32 * kk + lo];
      al[kk] = *(const f16x8*)&aldsl[16 * w + l15][32 * kk + lo];
    }
#pragma unroll
    for (int gg = 0; gg < 4; ++gg) {
      const int g = 4 * jb + gg;
      f32x4 acc = {0.f, 0.f, 0.f, 0.f};
#pragma unroll
      for (int kk = 0; kk < 8; ++kk) {
        f16x8 bh = *(const f16x8*)&WkTh[(16 * g + l15) * EE + 32 * kk + lo];
        f16x8 bl = *(const f16x8*)&WkTl[(16 * g + l15) * EE + 32 * kk + lo];
        acc = mfma16(ah[kk], bh, acc);
        acc = mfma16(al[kk], bh, acc);
        acc = mfma16(ah[kk], bl, acc);
      }
#pragma unroll
      for (int j = 0; j < 4; ++j) {
        const int mrow = 16 * w + 4 * (l >> 4) + j;
        const int ccol = 16 * g + l15;
        const int idx = b * (MM * CC) + mrow * CC + (ccol ^ (8 * (mrow & 7)));
        float v = acc[j];
        f16 h = (f16)v;
        K2h[idx] = h;
        K2l[idx] = (f16)(v - (float)h);
      }
    }
  } else {
    const int ct = 16 * (w + 4 * (jb - 2));
    f16x8 ah[8], al[8];
#pragma unroll
    for (int kk = 0; kk < 8; ++kk) {
      ah[kk] = *(const f16x8*)&WvTh[(ct + l15) * EE + 32 * kk + lo];
      al[kk] = *(const f16x8*)&WvTl[(ct + l15) * EE + 32 * kk + lo];
    }
#pragma unroll
    for (int g = 0; g < 4; ++g) {
      f32x4 acc = {0.f, 0.f, 0.f, 0.f};
#pragma unroll
      for (int kk = 0; kk < 8; ++kk) {
        f16x8 bh = *(const f16x8*)&aldsh[16 * g + l15][32 * kk + lo];
        f16x8 bl = *(const f16x8*)&aldsl[16 * g + l15][32 * kk + lo];
        acc = mfma16(ah[kk], bh, acc);
        acc = mfma16(al[kk], bh, acc);
        acc = mfma16(ah[kk], bl, acc);
      }
#pragma unroll
      for (int j = 0; j < 4; ++j) {
        const int crow = ct + 4 * (l >> 4) + j;
        const int mcol = 16 * g + l15;
        const int idx = b * (CC * MM) + crow * MM + (mcol ^ (8 * (crow & 7)));
        VTh[idx] = (f16)acc[j];
      }
    }
  }
}

// ---------------------------------------------------------------------------
// main: fused LN(q) + QK^T + softmax(M=64) + PV.
// Round-8 change: 512 threads / 8 waves / 128 q-rows per block -- the 48 KB
// stage + 2 barriers amortize over 2x rows (round-2 vs round-7 showed dur
// invariant at ~86us across MFMA count & occupancy: per-block fixed latency
// dominates). expf -> __expf (v_exp_f32; error irrelevant at 4x headroom).
// grid: 2048 blocks (XCD-bijective swizzle), LDS 48 KB, 2 blocks/CU.
// ---------------------------------------------------------------------------
__global__ __launch_bounds__(512, 4) void attn_kernel(
    const float* __restrict__ qin,
    const f16* __restrict__ K2hg, const f16* __restrict__ K2lg,
    const f16* __restrict__ VThg,
    const float* __restrict__ g2, const float* __restrict__ b2,
    float* __restrict__ outp) {
  __shared__ __align__(16) f16 k2h[MM * CC];  // 16 KB, swizzled; P reuses after S
  __shared__ __align__(16) f16 k2l[MM * CC];  // 16 KB
  __shared__ __align__(16) f16 vth[CC * MM];  // 16 KB, swizzled
  const int bid = blockIdx.x;
  const int swz = (bid & 7) * 256 + (bid >> 3);  // 2048%8==0: bijective
  const int b = swz >> 5, tile = swz & 31;       // 32 tiles of 128 rows
  const int t = threadIdx.x, l = t & 63, w = t >> 6;  // w in 0..7
  const int l15 = l & 15, lo = (l >> 4) * 8, swl = 8 * (l & 7);

  {  // stage K2 h/l + VT h: global layouts pre-swizzled -> linear copy
    const float4* __restrict__ skh = (const float4*)(K2hg + b * (MM * CC));
    const float4* __restrict__ skl = (const float4*)(K2lg + b * (MM * CC));
    const float4* __restrict__ svh = (const float4*)(VThg + b * (CC * MM));
#pragma unroll
    for (int i = 0; i < 2; ++i) {
      const int idx = t + 512 * i;
      ((float4*)k2h)[idx] = skh[idx];
      ((float4*)k2l)[idx] = skl[idx];
      ((float4*)vth)[idx] = svh[idx];
    }
  }

  // load Q in A-fragment layout: lane -> row l15, c-chunks by l>>4
  const int r = tile * 128 + 16 * w + l15;
  const float* __restrict__ qrow = qin + (b * NN + r) * CC;
  float x[4][8];
  float s1 = 0.f;
#pragma unroll
  for (int kk = 0; kk < 4; ++kk) {
    float4 v0 = *(const float4*)&qrow[32 * kk + lo];
    float4 v1 = *(const float4*)&qrow[32 * kk + lo + 4];
    x[kk][0] = v0.x; x[kk][1] = v0.y; x[kk][2] = v0.z; x[kk][3] = v0.w;
    x[kk][4] = v1.x; x[kk][5] = v1.y; x[kk][6] = v1.z; x[kk][7] = v1.w;
    s1 += v0.x + v0.y + v0.z + v0.w + v1.x + v1.y + v1.z + v1.w;
  }
  // row stats across lanes {l15, l15+16, l15+32, l15+48}
  s1 += __shfl_xor(s1, 16); s1 += __shfl_xor(s1, 32);
  const float mu = s1 * (1.f / CC);
  float s2 = 0.f;
#pragma unroll
  for (int kk = 0; kk < 4; ++kk)
#pragma unroll
    for (int j = 0; j < 8; ++j) { float d = x[kk][j] - mu; s2 += d * d; }
  s2 += __shfl_xor(s2, 16); s2 += __shfl_xor(s2, 32);
  const float rs = 1.f / sqrtf(s2 * (1.f / CC) + 1e-5f);

  // LN in fp32 + hi/lo split of q
  f16x8 aqh[4], aql[4];
#pragma unroll
  for (int kk = 0; kk < 4; ++kk) {
    float4 g0 = *(const float4*)&g2[32 * kk + lo];
    float4 g1v = *(const float4*)&g2[32 * kk + lo + 4];
    float4 c0 = *(const float4*)&b2[32 * kk + lo];
    float4 c1 = *(const float4*)&b2[32 * kk + lo + 4];
    float gg[8] = {g0.x, g0.y, g0.z, g0.w, g1v.x, g1v.y, g1v.z, g1v.w};
    float bb[8] = {c0.x, c0.y, c0.z, c0.w, c1.x, c1.y, c1.z, c1.w};
#pragma unroll
    for (int j = 0; j < 8; ++j) {
      float y = (x[kk][j] - mu) * rs * gg[j] + bb[j];
      f16 h = (f16)y;
      aqh[kk][j] = h;
      aql[kk][j] = (f16)(y - (float)h);
    }
  }
  __syncthreads();  // barrier 1: K2/VT staged

  // S = Q @ K2^T : 4 m-tiles x 4 k-steps x 3 hi/lo terms (LDS, swizzled)
  f32x4 sa[4];
#pragma unroll
  for (int g = 0; g < 4; ++g) sa[g] = (f32x4){0.f, 0.f, 0.f, 0.f};
#pragma unroll
  for (int g = 0; g < 4; ++g)
#pragma unroll
    for (int kk = 0; kk < 4; ++kk) {
      const int co = (16 * g + l15) * CC + ((32 * kk + lo) ^ swl);
      f16x8 bh = *(const f16x8*)&k2h[co];
      f16x8 bl = *(const f16x8*)&k2l[co];
      sa[g] = mfma16(aqh[kk], bh, sa[g]);
      sa[g] = mfma16(aql[kk], bh, sa[g]);
      sa[g] = mfma16(aqh[kk], bl, sa[g]);
    }

  // softmax over m (register-only; cols = 16g + l15, rows j in group l&15)
  float mx[4], rinv[4];
#pragma unroll
  for (int j = 0; j < 4; ++j) {
    float v = fmaxf(fmaxf(sa[0][j], sa[1][j]), fmaxf(sa[2][j], sa[3][j]));
    v = fmaxf(v, __shfl_xor(v, 1));
    v = fmaxf(v, __shfl_xor(v, 2));
    v = fmaxf(v, __shfl_xor(v, 4));
    v = fmaxf(v, __shfl_xor(v, 8));
    mx[j] = v;
  }
#pragma unroll
  for (int g = 0; g < 4; ++g)
#pragma unroll
    for (int j = 0; j < 4; ++j) sa[g][j] = __expf(sa[g][j] - mx[j]);
#pragma unroll
  for (int j = 0; j < 4; ++j) {
    float v = sa[0][j] + sa[1][j] + sa[2][j] + sa[3][j];
    v += __shfl_xor(v, 1);
    v += __shfl_xor(v, 2);
    v += __shfl_xor(v, 4);
    v += __shfl_xor(v, 8);
    rinv[j] = 1.f / v;
  }

  __syncthreads();  // barrier 2: all waves done reading k2h/k2l -> reuse for P

  // P (single f16) -> per-wave LDS transpose (reused k2h space), swizzled
  f16* __restrict__ plds = &k2h[w * 1024];  // 8 waves x 2 KB = 16 KB = k2h
#pragma unroll
  for (int g = 0; g < 4; ++g)
#pragma unroll
    for (int j = 0; j < 4; ++j) {
      const int rl = 4 * (l >> 4) + j;
      const int mc = 16 * g + l15;
      plds[rl * 64 + (mc ^ (8 * (rl & 7)))] = (f16)(sa[g][j] * rinv[j]);
    }
  asm volatile("s_waitcnt lgkmcnt(0)" ::: "memory");
  __builtin_amdgcn_sched_barrier(0);

  // O = P @ V : 8 c-tiles x 2 k-steps, single term (V h-only)
  f16x8 ap[2];
#pragma unroll
  for (int ks = 0; ks < 2; ++ks)
    ap[ks] = *(const f16x8*)&plds[l15 * 64 + ((32 * ks + lo) ^ swl)];
  f32x4 oa[8];
#pragma unroll
  for (int g = 0; g < 8; ++g) oa[g] = (f32x4){0.f, 0.f, 0.f, 0.f};
#pragma unroll
  for (int g = 0; g < 8; ++g)
#pragma unroll
    for (int ks = 0; ks < 2; ++ks) {
      f16x8 bv = *(const f16x8*)&vth[(16 * g + l15) * MM + ((32 * ks + lo) ^ swl)];
      oa[g] = mfma16(ap[ks], bv, oa[g]);
    }

  // store fp32 output
  const int rb = (b * NN + tile * 128 + 16 * w + 4 * (l >> 4)) * CC;
#pragma unroll
  for (int g = 0; g < 8; ++g)
#pragma unroll
    for (int j = 0; j < 4; ++j)
      outp[rb + j * CC + 16 * g + l15] = oa[g][j];
}

// ---------------------------------------------------------------------------
extern "C" void kernel_launch(void* const* d_in, const int* in_sizes, int n_in,
                              void* d_out, int out_size, void* d_ws, size_t ws_size,
                              hipStream_t stream) {
  (void)in_sizes; (void)n_in; (void)out_size; (void)ws_size;
  const float* q   = (const float*)d_in[0];
  const float* key = (const float*)d_in[1];
  const float* val = (const float*)d_in[2];
  const float* wk  = (const float*)d_in[3];
  const float* wv  = (const float*)d_in[4];
  const float* g1  = (const float*)d_in[5];
  const float* b1  = (const float*)d_in[6];
  const float* g2  = (const float*)d_in[7];
  const float* b2  = (const float*)d_in[8];
  float* out = (float*)d_out;

  char* ws = (char*)d_ws;
  f16* WkTh = (f16*)(ws);                           // 64 KB each
  f16* WkTl = (f16*)(ws + 65536);
  f16* WvTh = (f16*)(ws + 131072);
  f16* WvTl = (f16*)(ws + 196608);
  f16* K2h  = (f16*)(ws + 262144);                  // 1 MB each
  f16* K2l  = (f16*)(ws + 262144 + 1048576);
  f16* VTh  = (f16*)(ws + 262144 + 2097152);

  wt_kernel<<<8, 256, 0, stream>>>(wk, wv, WkTh, WkTl, WvTh, WvTl);
  prep_kernel<<<256, 256, 0, stream>>>(key, val, g1, b1, WkTh, WkTl, WvTh, WvTl,
                                       K2h, K2l, VTh);
  attn_kernel<<<2048, 512, 0, stream>>>(q, K2h, K2l, VTh, g2, b2, out);
}